// Round 4
// baseline (69.912 us; speedup 1.0000x reference)
//
#include <hip/hip_runtime.h>
#include <math.h>

#define N0 2048
#define N1 1024
#define M0T 32                     // 2048 / 64-row tiles
#define M1T 32                     // 1024 / 32-row tiles
#define NB0 (M0T * (M0T + 1) / 2)  // 528 lower-tri tile pairs, layer 0
#define NB1 (M1T * (M1T + 1) / 2)  // 528 lower-tri tile pairs, layer 1
#define NBLK0 (2 * NB0)            // 1056 blocks (each tile pair j-split in 2)
#define NBLK1 (2 * NB1)            // 1056 blocks
#define NBTOT (NBLK0 + NBLK1)      // 2112

// ws layout (floats): partial[NBTOT] only.
//
// R1 lesson: same-address device atomics serialize 2112 blocks (~25ns each) ->
//   separate finalize kernel, distinct-address partial stores.
// R2 lesson: top-5 dispatches are all 256MiB workspace-poison fills (39.8us);
//   controllable time is only ~20-25us of kernels + inter-kernel drains.
//   => fold prep INTO pairs (redundant per-block inversion of 96/48 tiny
//   matrices on otherwise-idle threads; pairs was latency-bound, VALUBusy 9%).
//   3 dispatches -> 2, no kn/inv global round-trip.
// R3: acquisition timeout — this source is the R2 proposal resubmitted
//   unchanged so the fusion actually gets measured.

__device__ __forceinline__ void tri_decode(int t, int& bi, int& bj) {
    int b = (int)((sqrtf(8.0f * t + 1.0f) - 1.0f) * 0.5f);
    while ((b + 1) * (b + 2) / 2 <= t) ++b;
    while (b * (b + 1) / 2 > t) --b;
    bi = b;
    bj = t - b * (b + 1) / 2;
}

// normalize + adjugate inverse + 1 Newton polish, 3x3, all fp32, reg-resident
__device__ __forceinline__ void inv3_to(const float* __restrict__ g, float* __restrict__ dst) {
    float a[9];
    float ss = 0.0f;
#pragma unroll
    for (int e = 0; e < 9; ++e) { a[e] = g[e]; ss = fmaf(a[e], a[e], ss); }
    float rn = 1.0f / (sqrtf(ss) + 1e-8f);
#pragma unroll
    for (int e = 0; e < 9; ++e) a[e] *= rn;
    float c00 = a[4] * a[8] - a[5] * a[7];
    float c01 = -(a[3] * a[8] - a[5] * a[6]);
    float c02 = a[3] * a[7] - a[4] * a[6];
    float det = a[0] * c00 + a[1] * c01 + a[2] * c02;
    float id = 1.0f / det;
    float x[9];
    x[0] = c00 * id;
    x[1] = (a[2] * a[7] - a[1] * a[8]) * id;
    x[2] = (a[1] * a[5] - a[2] * a[4]) * id;
    x[3] = c01 * id;
    x[4] = (a[0] * a[8] - a[2] * a[6]) * id;
    x[5] = (a[2] * a[3] - a[0] * a[5]) * id;
    x[6] = c02 * id;
    x[7] = (a[1] * a[6] - a[0] * a[7]) * id;
    x[8] = (a[0] * a[4] - a[1] * a[3]) * id;
    // Newton polish: x <- x(2I - a x)
    float r[9];
#pragma unroll
    for (int i = 0; i < 3; ++i)
#pragma unroll
        for (int j = 0; j < 3; ++j) {
            float m = a[i * 3 + 0] * x[0 * 3 + j];
            m = fmaf(a[i * 3 + 1], x[1 * 3 + j], m);
            m = fmaf(a[i * 3 + 2], x[2 * 3 + j], m);
            r[i * 3 + j] = ((i == j) ? 2.0f : 0.0f) - m;
        }
#pragma unroll
    for (int i = 0; i < 3; ++i)
#pragma unroll
        for (int j = 0; j < 3; ++j) {
            float m = x[i * 3 + 0] * r[0 * 3 + j];
            m = fmaf(x[i * 3 + 1], r[1 * 3 + j], m);
            m = fmaf(x[i * 3 + 2], r[2 * 3 + j], m);
            dst[i * 3 + j] = m;
        }
}

// normalize only, 3x3
__device__ __forceinline__ void norm3_to(const float* __restrict__ g, float* __restrict__ dst) {
    float a[9];
    float ss = 0.0f;
#pragma unroll
    for (int e = 0; e < 9; ++e) { a[e] = g[e]; ss = fmaf(a[e], a[e], ss); }
    float rn = 1.0f / (sqrtf(ss) + 1e-8f);
#pragma unroll
    for (int e = 0; e < 9; ++e) dst[e] = a[e] * rn;
}

// normalize + branchless GJ w/ partial pivot + 1 Newton polish, 5x5
__device__ __forceinline__ void inv5_to(const float* __restrict__ g, float* __restrict__ dst) {
    float A[5][5], B[5][5], K[5][5];
    float ss = 0.0f;
#pragma unroll
    for (int r = 0; r < 5; ++r)
#pragma unroll
        for (int c = 0; c < 5; ++c) {
            float v = g[r * 5 + c];
            A[r][c] = v;
            ss = fmaf(v, v, ss);
        }
    float rn = 1.0f / (sqrtf(ss) + 1e-8f);
#pragma unroll
    for (int r = 0; r < 5; ++r)
#pragma unroll
        for (int c = 0; c < 5; ++c) {
            A[r][c] *= rn;
            K[r][c] = A[r][c];
            B[r][c] = (r == c) ? 1.0f : 0.0f;
        }
#pragma unroll
    for (int k = 0; k < 5; ++k) {
#pragma unroll
        for (int r = k + 1; r < 5; ++r) {
            bool sw = fabsf(A[r][k]) > fabsf(A[k][k]);
#pragma unroll
            for (int c = k; c < 5; ++c) {
                float Ar = A[r][c], Ak = A[k][c];
                A[r][c] = sw ? Ak : Ar;
                A[k][c] = sw ? Ar : Ak;
            }
#pragma unroll
            for (int c = 0; c < 5; ++c) {
                float Br = B[r][c], Bk = B[k][c];
                B[r][c] = sw ? Bk : Br;
                B[k][c] = sw ? Br : Bk;
            }
        }
        float piv = 1.0f / A[k][k];
#pragma unroll
        for (int c = k; c < 5; ++c) A[k][c] *= piv;
#pragma unroll
        for (int c = 0; c < 5; ++c) B[k][c] *= piv;
#pragma unroll
        for (int r = 0; r < 5; ++r) {
            if (r == k) continue;
            float f = A[r][k];
#pragma unroll
            for (int c = k; c < 5; ++c) A[r][c] = fmaf(-f, A[k][c], A[r][c]);
#pragma unroll
            for (int c = 0; c < 5; ++c) B[r][c] = fmaf(-f, B[k][c], B[r][c]);
        }
    }
    // Newton polish: B <- B(2I - K B)
    float R[5][5];
#pragma unroll
    for (int i = 0; i < 5; ++i)
#pragma unroll
        for (int j = 0; j < 5; ++j) {
            float m = K[i][0] * B[0][j];
#pragma unroll
            for (int k = 1; k < 5; ++k) m = fmaf(K[i][k], B[k][j], m);
            R[i][j] = ((i == j) ? 2.0f : 0.0f) - m;
        }
#pragma unroll
    for (int i = 0; i < 5; ++i)
#pragma unroll
        for (int j = 0; j < 5; ++j) {
            float m = B[i][0] * R[0][j];
#pragma unroll
            for (int k = 1; k < 5; ++k) m = fmaf(B[i][k], R[k][j], m);
            dst[i * 5 + j] = m;
        }
}

// normalize only, 5x5
__device__ __forceinline__ void norm5_to(const float* __restrict__ g, float* __restrict__ dst) {
    float a[25];
    float ss = 0.0f;
#pragma unroll
    for (int e = 0; e < 25; ++e) { a[e] = g[e]; ss = fmaf(a[e], a[e], ss); }
    float rn = 1.0f / (sqrtf(ss) + 1e-8f);
#pragma unroll
    for (int e = 0; e < 25; ++e) dst[e] = a[e] * rn;
}

// ---------------------------------------------------------------------------
// Fused prep + pair-distance kernel, j-split triangular grid.
//   blocks [0, NBLK0):      layer 0 (d=3): 64x32 half-tile, 4x2 pairs/thread
//   blocks [NBLK0, NBTOT):  layer 1 (d=5): 32x16 half-tile, 2x1 pairs/thread
// Per block, threads 0..(Ninv-1) invert row-tile matrices from raw k, threads
// Ninv..(Ninv+Nnorm-1) normalize col-tile matrices; then all compute pairs.
// LDS-write audit: stride 9 (gcd(9,32)=1) and stride 25 (gcd(25,32)=1) ->
// all 32 lanes hit distinct banks. Read audit unchanged from R1 (conflict=0).
// ---------------------------------------------------------------------------
__global__ __launch_bounds__(256) void pairs_kernel(const float* __restrict__ k0,
                                                    const float* __restrict__ k1,
                                                    float* __restrict__ partial) {
    __shared__ __align__(16) float sA[800];  // L0: 64*9=576, L1: 32*25=800
    __shared__ __align__(16) float sB[400];  // L0: 32*9=288, L1: 16*25=400
    int tid = threadIdx.x;
    float contrib = 0.0f;

    if (blockIdx.x < NBLK0) {
        // ---------------- layer 0: d=3 ----------------
        int t = blockIdx.x;
        int pb = t >> 1, h = t & 1;
        int bi, bj;
        tri_decode(pb, bi, bj);

        // fused prep: rows -> inv in sA, cols -> kn in sB
        if (tid < 64) {
            inv3_to(k0 + (bi * 64 + tid) * 9, sA + tid * 9);
        } else if (tid < 96) {
            int j = tid - 64;
            norm3_to(k0 + (bj * 64 + h * 32 + j) * 9, sB + j * 9);
        }
        __syncthreads();

        int ti = tid >> 4, tj = tid & 15;
        int ibase = bi * 64 + ti * 4;
        int jbase = bj * 64 + h * 32 + tj * 2;
        float a[4][9];
#pragma unroll
        for (int u = 0; u < 4; ++u)
#pragma unroll
            for (int e = 0; e < 9; ++e) a[u][e] = sA[(ti * 4 + u) * 9 + e];
#pragma unroll
        for (int v = 0; v < 2; ++v) {
            float b[9];
#pragma unroll
            for (int e = 0; e < 9; ++e) b[e] = sB[(tj * 2 + v) * 9 + e];
#pragma unroll
            for (int u = 0; u < 4; ++u) {
                float s = 0.0f;
#pragma unroll
                for (int r = 0; r < 3; ++r)
#pragma unroll
                    for (int c = 0; c < 3; ++c) {
                        float m = a[u][r * 3 + 0] * b[c];
                        m = fmaf(a[u][r * 3 + 1], b[3 + c], m);
                        m = fmaf(a[u][r * 3 + 2], b[6 + c], m);
                        float d = ((r == c) ? 1.0f : 0.0f) - m;
                        s = fmaf(d, d, s);
                    }
                bool take = ((ibase + u) > (jbase + v)) && (s < 1.0f);
                contrib += take ? (1.0f - __builtin_amdgcn_sqrtf(s)) : 0.0f;
            }
        }
    } else {
        // ---------------- layer 1: d=5 ----------------
        int t = blockIdx.x - NBLK0;
        int pb = t >> 1, h = t & 1;
        int bi, bj;
        tri_decode(pb, bi, bj);

        // fused prep: rows -> inv in sA, cols -> kn in sB
        if (tid < 32) {
            inv5_to(k1 + (bi * 32 + tid) * 25, sA + tid * 25);
        } else if (tid < 48) {
            int j = tid - 32;
            norm5_to(k1 + (bj * 32 + h * 16 + j) * 25, sB + j * 25);
        }
        __syncthreads();

        int ti = tid >> 4, tj = tid & 15;  // ti: 2 rows each (32), tj: 1 col (16)
        int ibase = bi * 32 + ti * 2;
        int j = bj * 32 + h * 16 + tj;
        float a[2][25];
#pragma unroll
        for (int u = 0; u < 2; ++u)
#pragma unroll
            for (int e = 0; e < 25; ++e) a[u][e] = sA[(ti * 2 + u) * 25 + e];
        float b[25];
#pragma unroll
        for (int e = 0; e < 25; ++e) b[e] = sB[tj * 25 + e];
#pragma unroll
        for (int u = 0; u < 2; ++u) {
            float s = 0.0f;
#pragma unroll
            for (int r = 0; r < 5; ++r)
#pragma unroll
                for (int c = 0; c < 5; ++c) {
                    float m = a[u][r * 5 + 0] * b[c];
#pragma unroll
                    for (int k = 1; k < 5; ++k) m = fmaf(a[u][r * 5 + k], b[k * 5 + c], m);
                    float d = ((r == c) ? 1.0f : 0.0f) - m;
                    s = fmaf(d, d, s);
                }
            bool take = ((ibase + u) > j) && (s < 1.0f);
            contrib += take ? (1.0f - __builtin_amdgcn_sqrtf(s)) : 0.0f;
        }
    }

    // block reduction -> one partial per block, distinct address (no contention)
#pragma unroll
    for (int off = 32; off; off >>= 1) contrib += __shfl_down(contrib, off);
    __shared__ float wsum[4];
    if ((tid & 63) == 0) wsum[tid >> 6] = contrib;
    __syncthreads();
    if (tid == 0) partial[blockIdx.x] = wsum[0] + wsum[1] + wsum[2] + wsum[3];
}

__global__ void finalize_kernel(const float* __restrict__ partial, float* __restrict__ out) {
    int tid = threadIdx.x;
    double s0 = 0.0, s1 = 0.0;
    for (int x = tid; x < NBLK0; x += 256) s0 += (double)partial[x];
    for (int x = NBLK0 + tid; x < NBTOT; x += 256) s1 += (double)partial[x];
#pragma unroll
    for (int off = 32; off; off >>= 1) {
        s0 += __shfl_down(s0, off);
        s1 += __shfl_down(s1, off);
    }
    __shared__ double w0[4], w1[4];
    if ((tid & 63) == 0) { w0[tid >> 6] = s0; w1[tid >> 6] = s1; }
    __syncthreads();
    if (tid == 0) {
        double S0 = w0[0] + w0[1] + w0[2] + w0[3];
        double S1 = w1[0] + w1[1] + w1[2] + w1[3];
        // final = (2*S0/(n0(n0-1)) + 2*S1/(n1(n1-1))) / 2
        double res = S0 / ((double)N0 * (double)(N0 - 1)) +
                     S1 / ((double)N1 * (double)(N1 - 1));
        out[0] = (float)res;
    }
}

extern "C" void kernel_launch(void* const* d_in, const int* in_sizes, int n_in,
                              void* d_out, int out_size, void* d_ws, size_t ws_size,
                              hipStream_t stream) {
    const float* k0 = (const float*)d_in[0];  // (2048,3,3)
    const float* k1 = (const float*)d_in[1];  // (1024,5,5)
    float* out = (float*)d_out;

    float* partial = (float*)d_ws;  // 2112 floats

    pairs_kernel<<<NBTOT, 256, 0, stream>>>(k0, k1, partial);
    finalize_kernel<<<1, 256, 0, stream>>>(partial, out);
}

// Round 7
// 65.364 us; speedup vs baseline: 1.0696x; 1.0696x over previous
//
#include <hip/hip_runtime.h>
#include <math.h>

#define N0 2048
#define N1 1024
#define M0T 32                     // 2048 / 64-row tiles
#define M1T 32                     // 1024 / 32-row tiles
#define NB0 (M0T * (M0T + 1) / 2)  // 528 lower-tri tile pairs, layer 0 (64x64)
#define NB1 (M1T * (M1T + 1) / 2)  // 528 lower-tri tile pairs, layer 1 (32x32)
#define NBTOT (NB0 + NB1)          // 1056 blocks

// ws layout (floats): partial[NBTOT] only.
//
// Ledger:
// R1: fused same-address f64 atomics + fence serialized 2112 blocks (~25ns ea,
//     Occupancy 24% = straggler waves) -> separate finalize kernel.
// R2/R4: measured window = fill(39.6, fixed harness poison) + ~30 controllable.
// R4: prep-fusion (3->2 dispatches) was NET ZERO: saved boundary ~= pairs
//     slowdown from (a) inv5 serial chain w/ ~75 live VGPRs, (b) j-split
//     doubling prep redundancy.
// R5: un-split tiles (1056 blocks, prep/pair halves), drop 5x5 Newton
//     (pivoted GJ alone is reference-class fp32), keep 2-dispatch skeleton.
// R5/R6 bench: acquisition timeouts -> this source resubmitted UNCHANGED so
//     the R5 delta gets measured before any further edit.

__device__ __forceinline__ void tri_decode(int t, int& bi, int& bj) {
    int b = (int)((sqrtf(8.0f * t + 1.0f) - 1.0f) * 0.5f);
    while ((b + 1) * (b + 2) / 2 <= t) ++b;
    while (b * (b + 1) / 2 > t) --b;
    bi = b;
    bj = t - b * (b + 1) / 2;
}

// normalize + adjugate inverse + 1 Newton polish, 3x3, fp32 (cheap, keep polish)
__device__ __forceinline__ void inv3_to(const float* __restrict__ g, float* __restrict__ dst) {
    float a[9];
    float ss = 0.0f;
#pragma unroll
    for (int e = 0; e < 9; ++e) { a[e] = g[e]; ss = fmaf(a[e], a[e], ss); }
    float rn = 1.0f / (sqrtf(ss) + 1e-8f);
#pragma unroll
    for (int e = 0; e < 9; ++e) a[e] *= rn;
    float c00 = a[4] * a[8] - a[5] * a[7];
    float c01 = -(a[3] * a[8] - a[5] * a[6]);
    float c02 = a[3] * a[7] - a[4] * a[6];
    float det = a[0] * c00 + a[1] * c01 + a[2] * c02;
    float id = 1.0f / det;
    float x[9];
    x[0] = c00 * id;
    x[1] = (a[2] * a[7] - a[1] * a[8]) * id;
    x[2] = (a[1] * a[5] - a[2] * a[4]) * id;
    x[3] = c01 * id;
    x[4] = (a[0] * a[8] - a[2] * a[6]) * id;
    x[5] = (a[2] * a[3] - a[0] * a[5]) * id;
    x[6] = c02 * id;
    x[7] = (a[1] * a[6] - a[0] * a[7]) * id;
    x[8] = (a[0] * a[4] - a[1] * a[3]) * id;
    // Newton polish: x <- x(2I - a x)
    float r[9];
#pragma unroll
    for (int i = 0; i < 3; ++i)
#pragma unroll
        for (int j = 0; j < 3; ++j) {
            float m = a[i * 3 + 0] * x[0 * 3 + j];
            m = fmaf(a[i * 3 + 1], x[1 * 3 + j], m);
            m = fmaf(a[i * 3 + 2], x[2 * 3 + j], m);
            r[i * 3 + j] = ((i == j) ? 2.0f : 0.0f) - m;
        }
#pragma unroll
    for (int i = 0; i < 3; ++i)
#pragma unroll
        for (int j = 0; j < 3; ++j) {
            float m = x[i * 3 + 0] * r[0 * 3 + j];
            m = fmaf(x[i * 3 + 1], r[1 * 3 + j], m);
            m = fmaf(x[i * 3 + 2], r[2 * 3 + j], m);
            dst[i * 3 + j] = m;
        }
}

// normalize only, 3x3
__device__ __forceinline__ void norm3_to(const float* __restrict__ g, float* __restrict__ dst) {
    float a[9];
    float ss = 0.0f;
#pragma unroll
    for (int e = 0; e < 9; ++e) { a[e] = g[e]; ss = fmaf(a[e], a[e], ss); }
    float rn = 1.0f / (sqrtf(ss) + 1e-8f);
#pragma unroll
    for (int e = 0; e < 9; ++e) dst[e] = a[e] * rn;
}

// normalize + branchless GJ w/ partial pivot, 5x5, fp32.
// No Newton polish: pivoted GJ is the same error class as the reference's
// fp32 pivoted LU; dropping it cuts ~250 serial inst and 25 live VGPRs.
__device__ __forceinline__ void inv5_to(const float* __restrict__ g, float* __restrict__ dst) {
    float A[5][5], B[5][5];
    float ss = 0.0f;
#pragma unroll
    for (int r = 0; r < 5; ++r)
#pragma unroll
        for (int c = 0; c < 5; ++c) {
            float v = g[r * 5 + c];
            A[r][c] = v;
            ss = fmaf(v, v, ss);
        }
    float rn = 1.0f / (sqrtf(ss) + 1e-8f);
#pragma unroll
    for (int r = 0; r < 5; ++r)
#pragma unroll
        for (int c = 0; c < 5; ++c) {
            A[r][c] *= rn;
            B[r][c] = (r == c) ? 1.0f : 0.0f;
        }
#pragma unroll
    for (int k = 0; k < 5; ++k) {
#pragma unroll
        for (int r = k + 1; r < 5; ++r) {
            bool sw = fabsf(A[r][k]) > fabsf(A[k][k]);
#pragma unroll
            for (int c = k; c < 5; ++c) {
                float Ar = A[r][c], Ak = A[k][c];
                A[r][c] = sw ? Ak : Ar;
                A[k][c] = sw ? Ar : Ak;
            }
#pragma unroll
            for (int c = 0; c < 5; ++c) {
                float Br = B[r][c], Bk = B[k][c];
                B[r][c] = sw ? Bk : Br;
                B[k][c] = sw ? Br : Bk;
            }
        }
        float piv = 1.0f / A[k][k];
#pragma unroll
        for (int c = k; c < 5; ++c) A[k][c] *= piv;
#pragma unroll
        for (int c = 0; c < 5; ++c) B[k][c] *= piv;
#pragma unroll
        for (int r = 0; r < 5; ++r) {
            if (r == k) continue;
            float f = A[r][k];
#pragma unroll
            for (int c = k; c < 5; ++c) A[r][c] = fmaf(-f, A[k][c], A[r][c]);
#pragma unroll
            for (int c = 0; c < 5; ++c) B[r][c] = fmaf(-f, B[k][c], B[r][c]);
        }
    }
#pragma unroll
    for (int r = 0; r < 5; ++r)
#pragma unroll
        for (int c = 0; c < 5; ++c) dst[r * 5 + c] = B[r][c];
}

// normalize only, 5x5
__device__ __forceinline__ void norm5_to(const float* __restrict__ g, float* __restrict__ dst) {
    float a[25];
    float ss = 0.0f;
#pragma unroll
    for (int e = 0; e < 25; ++e) { a[e] = g[e]; ss = fmaf(a[e], a[e], ss); }
    float rn = 1.0f / (sqrtf(ss) + 1e-8f);
#pragma unroll
    for (int e = 0; e < 25; ++e) dst[e] = a[e] * rn;
}

// ---------------------------------------------------------------------------
// Fused prep + pair-distance kernel, FULL-tile triangular grid (un-split).
//   blocks [0, NB0):     layer 0 (d=3): 64x64 tile, 4x4 pairs/thread
//   blocks [NB0, NBTOT): layer 1 (d=5): 32x32 tile, 2x2 pairs/thread
// Un-split halves prep redundancy per pair vs the j-split R4 grid.
// Bank audit (64-lane wave, 32 banks):
//   writes: stride 9 / 25 floats (gcd(.,32)=1) -> 2-way across lane+32 (free).
//   L0 a-read: 4 ti-groups, stride 36f -> banks {0,4,8,12}+e, broadcast (free)
//   L0 b-read: 16 tj, stride 36f -> 8 banks x 2-way (free per m136)
//   L1 a/b-read: 16 groups, stride 50f -> 16 distinct banks (free)
// ---------------------------------------------------------------------------
__global__ __launch_bounds__(256) void pairs_kernel(const float* __restrict__ k0,
                                                    const float* __restrict__ k1,
                                                    float* __restrict__ partial) {
    __shared__ __align__(16) float sA[800];  // L0: 64*9=576, L1: 32*25=800
    __shared__ __align__(16) float sB[800];
    int tid = threadIdx.x;
    float contrib = 0.0f;

    if (blockIdx.x < NB0) {
        // ---------------- layer 0: d=3, 64x64 ----------------
        int bi, bj;
        tri_decode(blockIdx.x, bi, bj);

        // fused prep: 64 inversions + 64 normalizations from raw k0
        if (tid < 64) {
            inv3_to(k0 + (bi * 64 + tid) * 9, sA + tid * 9);
        } else if (tid < 128) {
            int j = tid - 64;
            norm3_to(k0 + (bj * 64 + j) * 9, sB + j * 9);
        }
        __syncthreads();

        int ti = tid >> 4, tj = tid & 15;
        int ibase = bi * 64 + ti * 4, jbase = bj * 64 + tj * 4;
        float a[4][9];
#pragma unroll
        for (int u = 0; u < 4; ++u)
#pragma unroll
            for (int e = 0; e < 9; ++e) a[u][e] = sA[(ti * 4 + u) * 9 + e];
#pragma unroll
        for (int v = 0; v < 4; ++v) {
            float b[9];
#pragma unroll
            for (int e = 0; e < 9; ++e) b[e] = sB[(tj * 4 + v) * 9 + e];
#pragma unroll
            for (int u = 0; u < 4; ++u) {
                float s = 0.0f;
#pragma unroll
                for (int r = 0; r < 3; ++r)
#pragma unroll
                    for (int c = 0; c < 3; ++c) {
                        float m = a[u][r * 3 + 0] * b[c];
                        m = fmaf(a[u][r * 3 + 1], b[3 + c], m);
                        m = fmaf(a[u][r * 3 + 2], b[6 + c], m);
                        float d = ((r == c) ? 1.0f : 0.0f) - m;
                        s = fmaf(d, d, s);
                    }
                bool take = ((ibase + u) > (jbase + v)) && (s < 1.0f);
                contrib += take ? (1.0f - __builtin_amdgcn_sqrtf(s)) : 0.0f;
            }
        }
    } else {
        // ---------------- layer 1: d=5, 32x32 ----------------
        int bi, bj;
        tri_decode(blockIdx.x - NB0, bi, bj);

        // fused prep: 32 inversions + 32 normalizations from raw k1
        if (tid < 32) {
            inv5_to(k1 + (bi * 32 + tid) * 25, sA + tid * 25);
        } else if (tid < 64) {
            int j = tid - 32;
            norm5_to(k1 + (bj * 32 + j) * 25, sB + j * 25);
        }
        __syncthreads();

        int ti = tid >> 4, tj = tid & 15;
        int ibase = bi * 32 + ti * 2, jbase = bj * 32 + tj * 2;
        float a[2][25];
#pragma unroll
        for (int u = 0; u < 2; ++u)
#pragma unroll
            for (int e = 0; e < 25; ++e) a[u][e] = sA[(ti * 2 + u) * 25 + e];
#pragma unroll
        for (int v = 0; v < 2; ++v) {
            float b[25];
#pragma unroll
            for (int e = 0; e < 25; ++e) b[e] = sB[(tj * 2 + v) * 25 + e];
#pragma unroll
            for (int u = 0; u < 2; ++u) {
                float s = 0.0f;
#pragma unroll
                for (int r = 0; r < 5; ++r)
#pragma unroll
                    for (int c = 0; c < 5; ++c) {
                        float m = a[u][r * 5 + 0] * b[c];
#pragma unroll
                        for (int k = 1; k < 5; ++k) m = fmaf(a[u][r * 5 + k], b[k * 5 + c], m);
                        float d = ((r == c) ? 1.0f : 0.0f) - m;
                        s = fmaf(d, d, s);
                    }
                bool take = ((ibase + u) > (jbase + v)) && (s < 1.0f);
                contrib += take ? (1.0f - __builtin_amdgcn_sqrtf(s)) : 0.0f;
            }
        }
    }

    // block reduction -> one partial per block, distinct address (no contention)
#pragma unroll
    for (int off = 32; off; off >>= 1) contrib += __shfl_down(contrib, off);
    __shared__ float wsum[4];
    if ((tid & 63) == 0) wsum[tid >> 6] = contrib;
    __syncthreads();
    if (tid == 0) partial[blockIdx.x] = wsum[0] + wsum[1] + wsum[2] + wsum[3];
}

__global__ void finalize_kernel(const float* __restrict__ partial, float* __restrict__ out) {
    int tid = threadIdx.x;
    double s0 = 0.0, s1 = 0.0;
    for (int x = tid; x < NB0; x += 256) s0 += (double)partial[x];
    for (int x = NB0 + tid; x < NBTOT; x += 256) s1 += (double)partial[x];
#pragma unroll
    for (int off = 32; off; off >>= 1) {
        s0 += __shfl_down(s0, off);
        s1 += __shfl_down(s1, off);
    }
    __shared__ double w0[4], w1[4];
    if ((tid & 63) == 0) { w0[tid >> 6] = s0; w1[tid >> 6] = s1; }
    __syncthreads();
    if (tid == 0) {
        double S0 = w0[0] + w0[1] + w0[2] + w0[3];
        double S1 = w1[0] + w1[1] + w1[2] + w1[3];
        // final = (2*S0/(n0(n0-1)) + 2*S1/(n1(n1-1))) / 2
        double res = S0 / ((double)N0 * (double)(N0 - 1)) +
                     S1 / ((double)N1 * (double)(N1 - 1));
        out[0] = (float)res;
    }
}

extern "C" void kernel_launch(void* const* d_in, const int* in_sizes, int n_in,
                              void* d_out, int out_size, void* d_ws, size_t ws_size,
                              hipStream_t stream) {
    const float* k0 = (const float*)d_in[0];  // (2048,3,3)
    const float* k1 = (const float*)d_in[1];  // (1024,5,5)
    float* out = (float*)d_out;

    float* partial = (float*)d_ws;  // 1056 floats

    pairs_kernel<<<NBTOT, 256, 0, stream>>>(k0, k1, partial);
    finalize_kernel<<<1, 256, 0, stream>>>(partial, out);
}